// Round 5
// baseline (3235.005 us; speedup 1.0000x reference)
//
#include <hip/hip_runtime.h>
#include <math.h>

// RG-LRU single-pass: B=4, L=8192, W=1024, H=8, bw=128.
#define NB 4
#define NL 8192
#define NW 1024
#define NH 8
#define BWID 128
#define POWERF 8.0f

#define TM 64                 // timesteps per block == scan chunk
#define NRC (NL / TM)         // 128 chunks per sequence
#define NCHAIN (NB * NH)      // 32 independent scan chains
#define NBLK (NRC * NCHAIN)   // 4096 blocks

typedef __attribute__((ext_vector_type(8))) short bf16x8;          // MFMA A/B frag
typedef __attribute__((ext_vector_type(8))) unsigned short u16x8;  // raw 16B move
typedef __attribute__((ext_vector_type(4))) float f32x4;           // MFMA C/D frag

__device__ __forceinline__ unsigned short bf_hi(float f) {
  return (unsigned short)(__float_as_uint(f) >> 16);  // truncate to bf16
}
__device__ __forceinline__ float bf_f(unsigned short h) {
  return __uint_as_float(((unsigned)h) << 16);
}

// ---------------- prep: W^T bf16 hi/lo, softplus(a_param), zero sync state --
// wt layout: [mat(2)][split(2)][h(8)][col(128)][k(128)] ushort (1 MB total).
__global__ void prep_kernel(const float* __restrict__ w_in,
                            const float* __restrict__ w_a,
                            const float* __restrict__ a_param,
                            unsigned short* __restrict__ wt,
                            float* __restrict__ sp,
                            int* __restrict__ flags,
                            int* __restrict__ ticket) {
  const int gtid = blockIdx.x * 256 + threadIdx.x;  // 0..262143
  const int k   = gtid & 127;
  const int col = (gtid >> 7) & 127;
  const int hh  = (gtid >> 14) & 7;
  const int mat = gtid >> 17;
  const float* src = mat ? w_a : w_in;
  const float v = src[((size_t)hh * 128 + k) * 128 + col];  // W[h][k][col]
  const unsigned short hi = bf_hi(v);
  const unsigned short lo = bf_hi(v - bf_f(hi));
  wt[(((size_t)(mat * 2 + 0) * 8 + hh) * 128 + col) * 128 + k] = hi;
  wt[(((size_t)(mat * 2 + 1) * 8 + hh) * 128 + col) * 128 + k] = lo;
  if (gtid < NW) sp[gtid] = log1pf(expf(a_param[gtid]));
  if (gtid < NBLK) flags[gtid] = 0;    // carry flags (visible at kernel end)
  if (gtid == 0) *ticket = 0;          // block ticket counter
}

// ---------------- fused: MFMA gates + local scan + chained carry + out ------
// Block = ticket-ordered (rc, bh): rc = vbid/32 (layer-major) so a block only
// waits on strictly-smaller tickets -> started blocks -> no deadlock.
// Phases: GEMM (identical to R4 gates) -> local scan (bit-identical) ->
// wait pred inclusive carry (agent-scope flag+payload; rocPRIM pattern) ->
// publish own carry (== scan_carry's fmaf) -> rescan chunk from hprev
// (== scan_final's chain) -> coalesced float4 store of out from LDS.
__global__ __launch_bounds__(256, 2)
void fused_kernel(const float* __restrict__ x,
                  const unsigned short* __restrict__ wt,
                  const float* __restrict__ sp,
                  const float* __restrict__ b_in,
                  const float* __restrict__ b_a,
                  float* __restrict__ out,
                  int* __restrict__ ticket,
                  int* __restrict__ flags,
                  float* __restrict__ hcarry) {
  __shared__ char smem[65536];
  char* const pXh = smem;            // 16 KB u16 [64][128] swz ((row&15)<<4)
  char* const pXl = smem + 16384;    // 16 KB
  char* const pW  = smem + 32768;    // 32 KB u16 [col(128)][arr(4)][kk(32)] swz
  char* const pA  = smem + 32768;    // 32 KB f32 [64][128] overlay (over sW)
  char* const pXn = smem;            // 32 KB f32 [64][128] overlay (over sX*)

  const int tid  = threadIdx.x;
  // ---- ticket: decouples work-id from dispatch order (smem is free here) ----
  if (tid == 0) *(int*)smem = atomicAdd(ticket, 1);
  __syncthreads();
  const int vbid = *(const int*)smem;
  __syncthreads();                   // vbid read by all before smem reuse
  const int rc = vbid >> 5;          // chunk index (layer-major)
  const int bh = vbid & 31;
  const int b  = bh >> 3;
  const int h  = bh & 7;

  const int lane = tid & 63;
  const int wid  = tid >> 6;
  const int g  = lane >> 4;   // k-group 0..3
  const int ln = lane & 15;
  const int wr = wid >> 1;    // row half (32 rows)
  const int wc = wid & 1;     // col half (64 cols)

  const size_t xbase = ((size_t)b * NL + (size_t)rc * TM) * NW + h * BWID;

  // ---- W prefetch addressing (8 chunks/thread, kt-independent) ----
  int wsoff[8], wdoff[8];
#pragma unroll
  for (int i = 0; i < 8; ++i) {
    const int chunk = tid + 256 * i;   // 0..2047
    const int arr = chunk >> 9;        // 0:in_hi 1:in_lo 2:a_hi 3:a_lo
    const int rem = chunk & 511;
    const int col = rem >> 2;
    const int kk8 = (rem & 3) * 8;
    wsoff[i] = (arr * 8 + h) * 16384 + col * 128 + kk8;  // + kt at use
    wdoff[i] = col * 256 + ((arr * 64 + kk8 * 2) ^ ((col & 15) << 4));
  }
  u16x8 wreg[8];
#pragma unroll
  for (int i = 0; i < 8; ++i) wreg[i] = *(const u16x8*)(wt + wsoff[i]);  // kt=0

  // ---- stage X as bf16 hi/lo (overlaps W[0] loads) ----
#pragma unroll
  for (int i = 0; i < 4; ++i) {
    const int chunk = tid + 256 * i;      // 0..1023
    const int row = chunk >> 4;
    const int k8  = (chunk & 15) * 8;
    const float4 v0 = *(const float4*)(x + xbase + (size_t)row * NW + k8);
    const float4 v1 = *(const float4*)(x + xbase + (size_t)row * NW + k8 + 4);
    const float f[8] = {v0.x, v0.y, v0.z, v0.w, v1.x, v1.y, v1.z, v1.w};
    u16x8 vh, vl;
#pragma unroll
    for (int j = 0; j < 8; ++j) {
      const unsigned short hi = bf_hi(f[j]);
      vh[j] = hi;
      vl[j] = bf_hi(f[j] - bf_f(hi));
    }
    const int off = row * 256 + ((k8 * 2) ^ ((row & 15) << 4));
    *(u16x8*)(pXh + off) = vh;
    *(u16x8*)(pXl + off) = vl;
  }
  __syncthreads();                 // X staged; sW untouched
#pragma unroll
  for (int i = 0; i < 8; ++i) *(u16x8*)(pW + wdoff[i]) = wreg[i];  // W[0]->LDS

  f32x4 accx[2][4], acca[2][4];
#pragma unroll
  for (int rt = 0; rt < 2; ++rt)
#pragma unroll
    for (int ct = 0; ct < 4; ++ct) {
      accx[rt][ct] = (f32x4){0.f, 0.f, 0.f, 0.f};
      acca[rt][ct] = (f32x4){0.f, 0.f, 0.f, 0.f};
    }

#pragma unroll 1
  for (int kt = 0; kt < BWID; kt += 32) {
    if (kt < 96) {                  // issue next-tile loads (latency hidden)
#pragma unroll
      for (int i = 0; i < 8; ++i)
        wreg[i] = *(const u16x8*)(wt + wsoff[i] + kt + 32);
    }
    __syncthreads();                // current W tile visible in sW

    bf16x8 Ah[2], Al[2];
#pragma unroll
    for (int rt = 0; rt < 2; ++rt) {
      const int arow = wr * 32 + rt * 16 + ln;
      const int abyte = arow * 256 + (((kt + g * 8) * 2) ^ ((arow & 15) << 4));
      Ah[rt] = *(const bf16x8*)(pXh + abyte);
      Al[rt] = *(const bf16x8*)(pXl + abyte);
    }
    const int cs = ln << 4;
    const int gk = g * 16;
#pragma unroll
    for (int ct = 0; ct < 4; ++ct) {
      const int cb = (wc * 64 + ct * 16 + ln) * 256;
      const bf16x8 Bih = *(const bf16x8*)(pW + cb + ((0   + gk) ^ cs));
      const bf16x8 Bil = *(const bf16x8*)(pW + cb + ((64  + gk) ^ cs));
      const bf16x8 Bah = *(const bf16x8*)(pW + cb + ((128 + gk) ^ cs));
      const bf16x8 Bal = *(const bf16x8*)(pW + cb + ((192 + gk) ^ cs));
#pragma unroll
      for (int rt = 0; rt < 2; ++rt) {
        accx[rt][ct] = __builtin_amdgcn_mfma_f32_16x16x32_bf16(Ah[rt], Bih, accx[rt][ct], 0, 0, 0);
        accx[rt][ct] = __builtin_amdgcn_mfma_f32_16x16x32_bf16(Al[rt], Bih, accx[rt][ct], 0, 0, 0);
        accx[rt][ct] = __builtin_amdgcn_mfma_f32_16x16x32_bf16(Ah[rt], Bil, accx[rt][ct], 0, 0, 0);
        acca[rt][ct] = __builtin_amdgcn_mfma_f32_16x16x32_bf16(Ah[rt], Bah, acca[rt][ct], 0, 0, 0);
        acca[rt][ct] = __builtin_amdgcn_mfma_f32_16x16x32_bf16(Al[rt], Bah, acca[rt][ct], 0, 0, 0);
        acca[rt][ct] = __builtin_amdgcn_mfma_f32_16x16x32_bf16(Ah[rt], Bal, acca[rt][ct], 0, 0, 0);
      }
    }
    __syncthreads();                // frag reads of this tile done
    if (kt < 96) {
#pragma unroll
      for (int i = 0; i < 8; ++i) *(u16x8*)(pW + wdoff[i]) = wreg[i];
    }
  }
  // after last iteration's barrier: sW free for pA overlay.

  // ---- epilogue stage 1: gates; av -> pA(LDS); xn kept in regs ----
  float xn_sav[2][4][4];
#pragma unroll
  for (int ct = 0; ct < 4; ++ct) {
    const int col = wc * 64 + ct * 16 + ln;
    const float bi  = b_in[h * BWID + col];
    const float ba  = b_a[h * BWID + col];
    const float spv = sp[h * BWID + col];
#pragma unroll
    for (int rt = 0; rt < 2; ++rt) {
#pragma unroll
      for (int r = 0; r < 4; ++r) {
        const int row = wr * 32 + rt * 16 + g * 4 + r;  // C/D layout (m89)
        const float zx = accx[rt][ct][r] + bi;
        const float za = acca[rt][ct][r] + ba;
        const int xoff = row * 256 + ((col * 2) ^ ((row & 15) << 4));
        const float xv = bf_f(*(const unsigned short*)(pXh + xoff)) +
                         bf_f(*(const unsigned short*)(pXl + xoff));
        const float gx = __builtin_amdgcn_rcpf(1.f + __expf(-zx));
        const float ga = __builtin_amdgcn_rcpf(1.f + __expf(-za));
        const float la = -POWERF * ga * spv;
        const float av = __expf(la);
        const float asq = __expf(2.f * la);
        const float xn = xv * gx * sqrtf(fmaxf(1.f - asq, 0.f));
        *(float*)(pA + row * 512 + ((col * 4) ^ ((row & 7) << 4))) = av;
        xn_sav[rt][ct][r] = xn;
      }
    }
  }
  __syncthreads();                  // all X (u16) reads done
  // ---- stage 2: xn -> pXn (over X area) ----
#pragma unroll
  for (int ct = 0; ct < 4; ++ct) {
    const int col = wc * 64 + ct * 16 + ln;
#pragma unroll
    for (int rt = 0; rt < 2; ++rt) {
#pragma unroll
      for (int r = 0; r < 4; ++r) {
        const int row = wr * 32 + rt * 16 + g * 4 + r;
        *(float*)(pXn + row * 512 + ((col * 4) ^ ((row & 7) << 4))) =
            xn_sav[rt][ct][r];
      }
    }
  }
  __syncthreads();

  // ---- local scan: threads 0..127, one channel each (== old scan_local) ----
  float Aal = 1.f, hend_ = 0.f;
  if (tid < 128) {
    const int w = tid;
#pragma unroll 4
    for (int t = 0; t < TM; ++t) {
      const int so = ((w * 4) ^ ((t & 7) << 4)) + t * 512;
      const float a  = *(const float*)(pA + so);
      const float xv = *(const float*)(pXn + so);
      hend_ = fmaf(a, hend_, xv);   // bit-identical order
      Aal *= a;
    }
  }

  // ---- wait for predecessor's inclusive carry (agent-scope) ----
  float hprev = 0.f;
  if (rc > 0) {
    if (tid == 0) {
      int spins = 0;
      while (__hip_atomic_load(&flags[vbid - NCHAIN], __ATOMIC_ACQUIRE,
                               __HIP_MEMORY_SCOPE_AGENT) == 0) {
        if (++spins > (1 << 20)) break;   // poison-on-timeout, never hang
        __builtin_amdgcn_s_sleep(2);
      }
    }
    __syncthreads();
    if (tid < 128)
      hprev = __hip_atomic_load(&hcarry[(size_t)(vbid - NCHAIN) * 128 + tid],
                                __ATOMIC_RELAXED, __HIP_MEMORY_SCOPE_AGENT);
  }

  // ---- publish own inclusive carry (== scan_carry's fmaf), then flag ----
  if (tid < 128) {
    const float hglob = fmaf(Aal, hprev, hend_);
    __hip_atomic_store(&hcarry[(size_t)vbid * 128 + tid], hglob,
                       __ATOMIC_RELAXED, __HIP_MEMORY_SCOPE_AGENT);
  }
  __threadfence();                  // payload visible agent-wide
  __syncthreads();                  // all payload lanes done before flag
  if (tid == 0)
    __hip_atomic_store(&flags[vbid], 1, __ATOMIC_RELEASE,
                       __HIP_MEMORY_SCOPE_AGENT);

  // ---- final rescan from hprev (== old scan_final), h in place over pXn ----
  if (tid < 128) {
    const int w = tid;
    float hh = hprev;
#pragma unroll 4
    for (int t = 0; t < TM; ++t) {
      const int so = ((w * 4) ^ ((t & 7) << 4)) + t * 512;
      const float a  = *(const float*)(pA + so);
      const float xv = *(const float*)(pXn + so);
      hh = fmaf(a, hh, xv);         // bit-identical order
      *(float*)(pXn + so) = hh;
    }
  }
  __syncthreads();

  // ---- coalesced float4 store of out from LDS ----
#pragma unroll
  for (int i = 0; i < 8; ++i) {
    const int idx = tid + 256 * i;        // 0..2047 float4 chunks
    const int row = idx >> 5;
    const int c4  = (idx & 31) * 4;
    const float4 hv =
        *(const float4*)(pXn + row * 512 + ((c4 * 4) ^ ((row & 7) << 4)));
    *(float4*)(out + xbase + (size_t)row * NW + c4) = hv;
  }
}

extern "C" void kernel_launch(void* const* d_in, const int* in_sizes, int n_in,
                              void* d_out, int out_size, void* d_ws, size_t ws_size,
                              hipStream_t stream) {
  const float* x       = (const float*)d_in[0];
  const float* a_param = (const float*)d_in[1];
  const float* w_in    = (const float*)d_in[2];
  const float* b_in    = (const float*)d_in[3];
  const float* w_a     = (const float*)d_in[4];
  const float* b_a     = (const float*)d_in[5];
  float* out = (float*)d_out;

  // Workspace (~3.2 MB): flags[4096] @0, ticket @16K, hcarry[4096][128] @32K,
  // wt (1 MB) + sp (4 KB) after. prep zeroes flags/ticket each launch, so
  // graph replays are self-resetting.
  char* ws = (char*)d_ws;
  int* flags    = (int*)ws;                              // 16 KB
  int* ticket   = (int*)(ws + 16384);
  float* hcarry = (float*)(ws + 32768);                  // 2 MB
  unsigned short* wt = (unsigned short*)(ws + 32768 + (2 << 20));  // 1 MB
  float* sp     = (float*)(ws + 32768 + (2 << 20) + (1 << 20));

  prep_kernel<<<1024, 256, 0, stream>>>(w_in, w_a, a_param, wt, sp,
                                        flags, ticket);
  fused_kernel<<<NBLK, 256, 0, stream>>>(x, wt, sp, b_in, b_a, out,
                                         ticket, flags, hcarry);
}

// Round 6
// 336.389 us; speedup vs baseline: 9.6169x; 9.6169x over previous
//
#include <hip/hip_runtime.h>
#include <math.h>

// RG-LRU single-pass: B=4, L=8192, W=1024, H=8, bw=128.
#define NB 4
#define NL 8192
#define NW 1024
#define NH 8
#define BWID 128
#define POWERF 8.0f

#define TM 64                 // timesteps per block == scan chunk
#define NRC (NL / TM)         // 128 chunks per sequence
#define NCHAIN (NB * NH)      // 32 independent scan chains
#define NBLK (NRC * NCHAIN)   // 4096 blocks

typedef __attribute__((ext_vector_type(8))) short bf16x8;          // MFMA A/B frag
typedef __attribute__((ext_vector_type(8))) unsigned short u16x8;  // raw 16B move
typedef __attribute__((ext_vector_type(4))) float f32x4;           // MFMA C/D frag

__device__ __forceinline__ unsigned short bf_hi(float f) {
  return (unsigned short)(__float_as_uint(f) >> 16);  // truncate to bf16
}
__device__ __forceinline__ float bf_f(unsigned short h) {
  return __uint_as_float(((unsigned)h) << 16);
}

// ---------------- prep: W^T bf16 hi/lo, softplus(a_param), zero sync state --
// wt layout: [mat(2)][split(2)][h(8)][col(128)][k(128)] ushort (1 MB total).
// Also zeroes the 4 MB tagged-carry array (graph replays self-reset).
__global__ void prep_kernel(const float* __restrict__ w_in,
                            const float* __restrict__ w_a,
                            const float* __restrict__ a_param,
                            unsigned short* __restrict__ wt,
                            float* __restrict__ sp,
                            unsigned long long* __restrict__ hcarry,
                            int* __restrict__ ticket) {
  const int gtid = blockIdx.x * 256 + threadIdx.x;  // 0..262143
  const int k   = gtid & 127;
  const int col = (gtid >> 7) & 127;
  const int hh  = (gtid >> 14) & 7;
  const int mat = gtid >> 17;
  const float* src = mat ? w_a : w_in;
  const float v = src[((size_t)hh * 128 + k) * 128 + col];  // W[h][k][col]
  const unsigned short hi = bf_hi(v);
  const unsigned short lo = bf_hi(v - bf_f(hi));
  wt[(((size_t)(mat * 2 + 0) * 8 + hh) * 128 + col) * 128 + k] = hi;
  wt[(((size_t)(mat * 2 + 1) * 8 + hh) * 128 + col) * 128 + k] = lo;
  if (gtid < NW) sp[gtid] = log1pf(expf(a_param[gtid]));
  // zero 2 carry words/thread: covers NBLK*128 = 524288 words (4 MB)
  const size_t ci = (size_t)gtid * 2;
  hcarry[ci] = 0ull;
  hcarry[ci + 1] = 0ull;
  if (gtid == 0) *ticket = 0;          // block ticket counter
}

// ---------------- fused: MFMA gates + local scan + chained carry + out ------
// Block = ticket-ordered (rc, bh): rc = vbid/32 (layer-major) so a block only
// waits on strictly-smaller tickets -> started blocks -> no deadlock.
// Carry sync = per-channel tagged u64 (tag<<32 | float bits), RELAXED
// agent-scope atomics ONLY: tag+data are one naturally-atomic 8B word, so no
// acquire/release/fence is needed -> no per-poll L2 invalidate, no per-publish
// L2 writeback (the R5 hop cost). Wait+publish+rescan are per-thread.
__global__ __launch_bounds__(256, 2)
void fused_kernel(const float* __restrict__ x,
                  const unsigned short* __restrict__ wt,
                  const float* __restrict__ sp,
                  const float* __restrict__ b_in,
                  const float* __restrict__ b_a,
                  float* __restrict__ out,
                  int* __restrict__ ticket,
                  unsigned long long* __restrict__ hcarry) {
  __shared__ char smem[65536];
  char* const pXh = smem;            // 16 KB u16 [64][128] swz ((row&15)<<4)
  char* const pXl = smem + 16384;    // 16 KB
  char* const pW  = smem + 32768;    // 32 KB u16 [col(128)][arr(4)][kk(32)] swz
  char* const pA  = smem + 32768;    // 32 KB f32 [64][128] overlay (over sW)
  char* const pXn = smem;            // 32 KB f32 [64][128] overlay (over sX*)

  const int tid  = threadIdx.x;
  // ---- ticket: decouples work-id from dispatch order (smem is free here) ----
  if (tid == 0) *(int*)smem = atomicAdd(ticket, 1);
  __syncthreads();
  const int vbid = *(const int*)smem;
  __syncthreads();                   // vbid read by all before smem reuse
  const int rc = vbid >> 5;          // chunk index (layer-major)
  const int bh = vbid & 31;
  const int b  = bh >> 3;
  const int h  = bh & 7;

  const int lane = tid & 63;
  const int wid  = tid >> 6;
  const int g  = lane >> 4;   // k-group 0..3
  const int ln = lane & 15;
  const int wr = wid >> 1;    // row half (32 rows)
  const int wc = wid & 1;     // col half (64 cols)

  const size_t xbase = ((size_t)b * NL + (size_t)rc * TM) * NW + h * BWID;

  // ---- W prefetch addressing (8 chunks/thread, kt-independent) ----
  int wsoff[8], wdoff[8];
#pragma unroll
  for (int i = 0; i < 8; ++i) {
    const int chunk = tid + 256 * i;   // 0..2047
    const int arr = chunk >> 9;        // 0:in_hi 1:in_lo 2:a_hi 3:a_lo
    const int rem = chunk & 511;
    const int col = rem >> 2;
    const int kk8 = (rem & 3) * 8;
    wsoff[i] = (arr * 8 + h) * 16384 + col * 128 + kk8;  // + kt at use
    wdoff[i] = col * 256 + ((arr * 64 + kk8 * 2) ^ ((col & 15) << 4));
  }
  u16x8 wreg[8];
#pragma unroll
  for (int i = 0; i < 8; ++i) wreg[i] = *(const u16x8*)(wt + wsoff[i]);  // kt=0

  // ---- stage X as bf16 hi/lo (overlaps W[0] loads) ----
#pragma unroll
  for (int i = 0; i < 4; ++i) {
    const int chunk = tid + 256 * i;      // 0..1023
    const int row = chunk >> 4;
    const int k8  = (chunk & 15) * 8;
    const float4 v0 = *(const float4*)(x + xbase + (size_t)row * NW + k8);
    const float4 v1 = *(const float4*)(x + xbase + (size_t)row * NW + k8 + 4);
    const float f[8] = {v0.x, v0.y, v0.z, v0.w, v1.x, v1.y, v1.z, v1.w};
    u16x8 vh, vl;
#pragma unroll
    for (int j = 0; j < 8; ++j) {
      const unsigned short hi = bf_hi(f[j]);
      vh[j] = hi;
      vl[j] = bf_hi(f[j] - bf_f(hi));
    }
    const int off = row * 256 + ((k8 * 2) ^ ((row & 15) << 4));
    *(u16x8*)(pXh + off) = vh;
    *(u16x8*)(pXl + off) = vl;
  }
  __syncthreads();                 // X staged; sW untouched
#pragma unroll
  for (int i = 0; i < 8; ++i) *(u16x8*)(pW + wdoff[i]) = wreg[i];  // W[0]->LDS

  f32x4 accx[2][4], acca[2][4];
#pragma unroll
  for (int rt = 0; rt < 2; ++rt)
#pragma unroll
    for (int ct = 0; ct < 4; ++ct) {
      accx[rt][ct] = (f32x4){0.f, 0.f, 0.f, 0.f};
      acca[rt][ct] = (f32x4){0.f, 0.f, 0.f, 0.f};
    }

#pragma unroll 1
  for (int kt = 0; kt < BWID; kt += 32) {
    if (kt < 96) {                  // issue next-tile loads (latency hidden)
#pragma unroll
      for (int i = 0; i < 8; ++i)
        wreg[i] = *(const u16x8*)(wt + wsoff[i] + kt + 32);
    }
    __syncthreads();                // current W tile visible in sW

    bf16x8 Ah[2], Al[2];
#pragma unroll
    for (int rt = 0; rt < 2; ++rt) {
      const int arow = wr * 32 + rt * 16 + ln;
      const int abyte = arow * 256 + (((kt + g * 8) * 2) ^ ((arow & 15) << 4));
      Ah[rt] = *(const bf16x8*)(pXh + abyte);
      Al[rt] = *(const bf16x8*)(pXl + abyte);
    }
    const int cs = ln << 4;
    const int gk = g * 16;
#pragma unroll
    for (int ct = 0; ct < 4; ++ct) {
      const int cb = (wc * 64 + ct * 16 + ln) * 256;
      const bf16x8 Bih = *(const bf16x8*)(pW + cb + ((0   + gk) ^ cs));
      const bf16x8 Bil = *(const bf16x8*)(pW + cb + ((64  + gk) ^ cs));
      const bf16x8 Bah = *(const bf16x8*)(pW + cb + ((128 + gk) ^ cs));
      const bf16x8 Bal = *(const bf16x8*)(pW + cb + ((192 + gk) ^ cs));
#pragma unroll
      for (int rt = 0; rt < 2; ++rt) {
        accx[rt][ct] = __builtin_amdgcn_mfma_f32_16x16x32_bf16(Ah[rt], Bih, accx[rt][ct], 0, 0, 0);
        accx[rt][ct] = __builtin_amdgcn_mfma_f32_16x16x32_bf16(Al[rt], Bih, accx[rt][ct], 0, 0, 0);
        accx[rt][ct] = __builtin_amdgcn_mfma_f32_16x16x32_bf16(Ah[rt], Bil, accx[rt][ct], 0, 0, 0);
        acca[rt][ct] = __builtin_amdgcn_mfma_f32_16x16x32_bf16(Ah[rt], Bah, acca[rt][ct], 0, 0, 0);
        acca[rt][ct] = __builtin_amdgcn_mfma_f32_16x16x32_bf16(Al[rt], Bah, acca[rt][ct], 0, 0, 0);
        acca[rt][ct] = __builtin_amdgcn_mfma_f32_16x16x32_bf16(Ah[rt], Bal, acca[rt][ct], 0, 0, 0);
      }
    }
    __syncthreads();                // frag reads of this tile done
    if (kt < 96) {
#pragma unroll
      for (int i = 0; i < 8; ++i) *(u16x8*)(pW + wdoff[i]) = wreg[i];
    }
  }
  // after last iteration's barrier: sW free for pA overlay.

  // ---- epilogue stage 1: gates; av -> pA(LDS); xn kept in regs ----
  float xn_sav[2][4][4];
#pragma unroll
  for (int ct = 0; ct < 4; ++ct) {
    const int col = wc * 64 + ct * 16 + ln;
    const float bi  = b_in[h * BWID + col];
    const float ba  = b_a[h * BWID + col];
    const float spv = sp[h * BWID + col];
#pragma unroll
    for (int rt = 0; rt < 2; ++rt) {
#pragma unroll
      for (int r = 0; r < 4; ++r) {
        const int row = wr * 32 + rt * 16 + g * 4 + r;  // C/D layout (m89)
        const float zx = accx[rt][ct][r] + bi;
        const float za = acca[rt][ct][r] + ba;
        const int xoff = row * 256 + ((col * 2) ^ ((row & 15) << 4));
        const float xv = bf_f(*(const unsigned short*)(pXh + xoff)) +
                         bf_f(*(const unsigned short*)(pXl + xoff));
        const float gx = __builtin_amdgcn_rcpf(1.f + __expf(-zx));
        const float ga = __builtin_amdgcn_rcpf(1.f + __expf(-za));
        const float la = -POWERF * ga * spv;
        const float av = __expf(la);
        const float asq = __expf(2.f * la);
        const float xn = xv * gx * sqrtf(fmaxf(1.f - asq, 0.f));
        *(float*)(pA + row * 512 + ((col * 4) ^ ((row & 7) << 4))) = av;
        xn_sav[rt][ct][r] = xn;
      }
    }
  }
  __syncthreads();                  // all X (u16) reads done
  // ---- stage 2: xn -> pXn (over X area) ----
#pragma unroll
  for (int ct = 0; ct < 4; ++ct) {
    const int col = wc * 64 + ct * 16 + ln;
#pragma unroll
    for (int rt = 0; rt < 2; ++rt) {
#pragma unroll
      for (int r = 0; r < 4; ++r) {
        const int row = wr * 32 + rt * 16 + g * 4 + r;
        *(float*)(pXn + row * 512 + ((col * 4) ^ ((row & 7) << 4))) =
            xn_sav[rt][ct][r];
      }
    }
  }
  __syncthreads();

  // ---- per-thread: local scan, tagged-carry wait/publish, rescan ----
  if (tid < 128) {
    const int w = tid;
    float Aal = 1.f, hend_ = 0.f;
#pragma unroll 4
    for (int t = 0; t < TM; ++t) {
      const int so = ((w * 4) ^ ((t & 7) << 4)) + t * 512;
      const float a  = *(const float*)(pA + so);
      const float xv = *(const float*)(pXn + so);
      hend_ = fmaf(a, hend_, xv);   // bit-identical order (== old scan_local)
      Aal *= a;
    }

    float hprev = 0.f;
    if (rc > 0) {
      const unsigned long long* srcw =
          hcarry + (size_t)(vbid - NCHAIN) * 128 + w;
      unsigned long long wv = __hip_atomic_load(srcw, __ATOMIC_RELAXED,
                                                __HIP_MEMORY_SCOPE_AGENT);
      int spins = 0;
      while ((wv >> 32) == 0ull) {
        __builtin_amdgcn_s_sleep(1);
        if (++spins > (1 << 18)) break;   // poison-on-timeout, never hang
        wv = __hip_atomic_load(srcw, __ATOMIC_RELAXED,
                               __HIP_MEMORY_SCOPE_AGENT);
      }
      hprev = __uint_as_float((unsigned)(wv & 0xffffffffull));
    }

    // publish inclusive carry (== old scan_carry's fmaf), tag in high word
    const float hglob = fmaf(Aal, hprev, hend_);
    __hip_atomic_store(hcarry + (size_t)vbid * 128 + w,
                       (1ull << 32) | (unsigned long long)__float_as_uint(hglob),
                       __ATOMIC_RELAXED, __HIP_MEMORY_SCOPE_AGENT);

    // final rescan from hprev (== old scan_final), h in place over pXn
    float hh = hprev;
#pragma unroll 4
    for (int t = 0; t < TM; ++t) {
      const int so = ((w * 4) ^ ((t & 7) << 4)) + t * 512;
      const float a  = *(const float*)(pA + so);
      const float xv = *(const float*)(pXn + so);
      hh = fmaf(a, hh, xv);         // bit-identical order
      *(float*)(pXn + so) = hh;
    }
  }
  __syncthreads();

  // ---- coalesced float4 store of out from LDS ----
#pragma unroll
  for (int i = 0; i < 8; ++i) {
    const int idx = tid + 256 * i;        // 0..2047 float4 chunks
    const int row = idx >> 5;
    const int c4  = (idx & 31) * 4;
    const float4 hv =
        *(const float4*)(pXn + row * 512 + ((c4 * 4) ^ ((row & 7) << 4)));
    *(float4*)(out + xbase + (size_t)row * NW + c4) = hv;
  }
}

extern "C" void kernel_launch(void* const* d_in, const int* in_sizes, int n_in,
                              void* d_out, int out_size, void* d_ws, size_t ws_size,
                              hipStream_t stream) {
  const float* x       = (const float*)d_in[0];
  const float* a_param = (const float*)d_in[1];
  const float* w_in    = (const float*)d_in[2];
  const float* b_in    = (const float*)d_in[3];
  const float* w_a     = (const float*)d_in[4];
  const float* b_a     = (const float*)d_in[5];
  float* out = (float*)d_out;

  // Workspace (~5.3 MB): hcarry[4096*128] u64 @0 (4 MB), ticket, wt (1 MB),
  // sp (4 KB). prep re-zeroes hcarry/ticket each launch (graph-replay safe).
  char* ws = (char*)d_ws;
  unsigned long long* hcarry = (unsigned long long*)ws;        // 4 MB
  int* ticket = (int*)(ws + (4 << 20));
  unsigned short* wt = (unsigned short*)(ws + (4 << 20) + 1024);  // 1 MB
  float* sp = (float*)(ws + (4 << 20) + 1024 + (1 << 20));

  prep_kernel<<<1024, 256, 0, stream>>>(w_in, w_a, a_param, wt, sp,
                                        hcarry, ticket);
  fused_kernel<<<NBLK, 256, 0, stream>>>(x, wt, sp, b_in, b_a, out,
                                         ticket, hcarry);
}

// Round 7
// 318.361 us; speedup vs baseline: 10.1614x; 1.0566x over previous
//
#include <hip/hip_runtime.h>
#include <math.h>

// RG-LRU single-pass: B=4, L=8192, W=1024, H=8, bw=128.
#define NB 4
#define NL 8192
#define NW 1024
#define NH 8
#define BWID 128
#define POWERF 8.0f

#define TM 64                 // timesteps per block == scan chunk
#define NRC (NL / TM)         // 128 chunks per sequence
#define NCHAIN (NB * NH)      // 32 independent scan chains
#define NBLK (NRC * NCHAIN)   // 4096 blocks

typedef __attribute__((ext_vector_type(8))) short bf16x8;          // MFMA A/B frag
typedef __attribute__((ext_vector_type(8))) unsigned short u16x8;  // raw 16B move
typedef __attribute__((ext_vector_type(4))) float f32x4;           // MFMA C/D frag

__device__ __forceinline__ unsigned short bf_hi(float f) {
  return (unsigned short)(__float_as_uint(f) >> 16);  // truncate to bf16
}
__device__ __forceinline__ float bf_f(unsigned short h) {
  return __uint_as_float(((unsigned)h) << 16);
}

// ---------------- prep: W^T bf16 hi/lo, softplus(a_param), zero sync state --
// wt layout: [mat(2)][split(2)][h(8)][col(128)][k(128)] ushort (1 MB total).
__global__ void prep_kernel(const float* __restrict__ w_in,
                            const float* __restrict__ w_a,
                            const float* __restrict__ a_param,
                            unsigned short* __restrict__ wt,
                            float* __restrict__ sp,
                            unsigned long long* __restrict__ hcarry,
                            int* __restrict__ ticket) {
  const int gtid = blockIdx.x * 256 + threadIdx.x;  // 0..262143
  const int k   = gtid & 127;
  const int col = (gtid >> 7) & 127;
  const int hh  = (gtid >> 14) & 7;
  const int mat = gtid >> 17;
  const float* src = mat ? w_a : w_in;
  const float v = src[((size_t)hh * 128 + k) * 128 + col];  // W[h][k][col]
  const unsigned short hi = bf_hi(v);
  const unsigned short lo = bf_hi(v - bf_f(hi));
  wt[(((size_t)(mat * 2 + 0) * 8 + hh) * 128 + col) * 128 + k] = hi;
  wt[(((size_t)(mat * 2 + 1) * 8 + hh) * 128 + col) * 128 + k] = lo;
  if (gtid < NW) sp[gtid] = log1pf(expf(a_param[gtid]));
  const size_t ci = (size_t)gtid * 2;   // zero NBLK*128 tagged words (4 MB)
  hcarry[ci] = 0ull;
  hcarry[ci + 1] = 0ull;
  if (gtid == 0) *ticket = 0;
}

// ---------------- fused: MFMA gates + segmented scan + chained carry --------
// 48 KB LDS -> 3 blocks/CU (vs 64 KB / 2): pXh 16K + pXl 16K + pW 16K.
// GEMM: one matrix per phase (W_in[kt] then W_a[kt]); A-frags read once per
// kt and reused across the pair; next phase's W tile reg-prefetched.
// Epilogue (register-first): gates -> av/xn regs; per-thread 4-row segment
// partials (A4,h4) -> pSeg (16K over dead pW); scan threads compose 16
// segments/channel (affine compose == scan_carry math), poll/publish tagged
// u64 carry (R6 protocol unchanged), write prefix-h back; owners rescan
// their 4 rows from the prefix and store out from regs.
__global__ __launch_bounds__(256, 3)
void fused_kernel(const float* __restrict__ x,
                  const unsigned short* __restrict__ wt,
                  const float* __restrict__ sp,
                  const float* __restrict__ b_in,
                  const float* __restrict__ b_a,
                  float* __restrict__ out,
                  int* __restrict__ ticket,
                  unsigned long long* __restrict__ hcarry) {
  __shared__ char smem[49152];
  char* const pXh = smem;            // 16 KB u16 [64][128] swz ((row&15)<<4)
  char* const pXl = smem + 16384;    // 16 KB
  char* const pW  = smem + 32768;    // 16 KB u16 [col(128)][split(2)][kk(32)] swz
  char* const pSeg = smem + 32768;   // 16 KB f32x2 [col(128)][seg(16)] (over pW)

  const int tid  = threadIdx.x;
  // ---- ticket: decouples work-id from dispatch order ----
  if (tid == 0) *(int*)smem = atomicAdd(ticket, 1);
  __syncthreads();
  const int vbid = *(const int*)smem;
  __syncthreads();                   // vbid read by all before smem reuse
  const int rc = vbid >> 5;          // chunk index (layer-major: no deadlock)
  const int bh = vbid & 31;
  const int b  = bh >> 3;
  const int h  = bh & 7;

  const int lane = tid & 63;
  const int wid  = tid >> 6;
  const int g  = lane >> 4;   // k-group 0..3
  const int ln = lane & 15;
  const int wr = wid >> 1;    // row half (32 rows)
  const int wc = wid & 1;     // col half (64 cols)

  const size_t xbase = ((size_t)b * NL + (size_t)rc * TM) * NW + h * BWID;

  // ---- W stage addressing: 1024 16B chunks/phase = 4/thread ----
  int wsoff[4], wdoff[4];
#pragma unroll
  for (int i = 0; i < 4; ++i) {
    const int chunk = tid + 256 * i;   // 0..1023
    const int split = chunk >> 9;      // 0:hi 1:lo
    const int rem = chunk & 511;
    const int col = rem >> 2;
    const int kk8 = (rem & 3) * 8;
    wsoff[i] = split * 131072 + h * 16384 + col * 128 + kk8;  // +mat*262144+kt
    wdoff[i] = col * 128 + ((split * 64 + kk8 * 2) ^ ((col & 7) << 4));
  }
  u16x8 wreg[4];
#pragma unroll
  for (int i = 0; i < 4; ++i) wreg[i] = *(const u16x8*)(wt + wsoff[i]);  // Win[0]

  // ---- stage X as bf16 hi/lo (overlaps W loads) ----
#pragma unroll
  for (int i = 0; i < 4; ++i) {
    const int chunk = tid + 256 * i;      // 0..1023
    const int row = chunk >> 4;
    const int k8  = (chunk & 15) * 8;
    const float4 v0 = *(const float4*)(x + xbase + (size_t)row * NW + k8);
    const float4 v1 = *(const float4*)(x + xbase + (size_t)row * NW + k8 + 4);
    const float f[8] = {v0.x, v0.y, v0.z, v0.w, v1.x, v1.y, v1.z, v1.w};
    u16x8 vh, vl;
#pragma unroll
    for (int j = 0; j < 8; ++j) {
      const unsigned short hi = bf_hi(f[j]);
      vh[j] = hi;
      vl[j] = bf_hi(f[j] - bf_f(hi));
    }
    const int off = row * 256 + ((k8 * 2) ^ ((row & 15) << 4));
    *(u16x8*)(pXh + off) = vh;
    *(u16x8*)(pXl + off) = vl;
  }
  __syncthreads();                 // X staged; pW untouched
#pragma unroll
  for (int i = 0; i < 4; ++i) *(u16x8*)(pW + wdoff[i]) = wreg[i];  // Win[0]
#pragma unroll
  for (int i = 0; i < 4; ++i)
    wreg[i] = *(const u16x8*)(wt + wsoff[i] + 262144);             // Wa[0]

  f32x4 accx[2][4], acca[2][4];
#pragma unroll
  for (int rt = 0; rt < 2; ++rt)
#pragma unroll
    for (int ct = 0; ct < 4; ++ct) {
      accx[rt][ct] = (f32x4){0.f, 0.f, 0.f, 0.f};
      acca[rt][ct] = (f32x4){0.f, 0.f, 0.f, 0.f};
    }

  const int csw = (ln & 7) << 4;     // B-frag swizzle (col&7 == ln&7)
  const int gk  = g * 16;

#pragma unroll 1
  for (int j = 0; j < 4; ++j) {
    const int kt = j * 32;
    __syncthreads();                 // pW = Win[j]
    bf16x8 Ah[2], Al[2];
#pragma unroll
    for (int rt = 0; rt < 2; ++rt) {
      const int arow = wr * 32 + rt * 16 + ln;
      const int abyte = arow * 256 + (((kt + g * 8) * 2) ^ ((arow & 15) << 4));
      Ah[rt] = *(const bf16x8*)(pXh + abyte);
      Al[rt] = *(const bf16x8*)(pXl + abyte);
    }
#pragma unroll
    for (int ct = 0; ct < 4; ++ct) {
      const int cb = (wc * 64 + ct * 16 + ln) * 128;
      const bf16x8 Bh = *(const bf16x8*)(pW + cb + ((gk) ^ csw));
      const bf16x8 Bl = *(const bf16x8*)(pW + cb + ((64 + gk) ^ csw));
#pragma unroll
      for (int rt = 0; rt < 2; ++rt) {
        accx[rt][ct] = __builtin_amdgcn_mfma_f32_16x16x32_bf16(Ah[rt], Bh, accx[rt][ct], 0, 0, 0);
        accx[rt][ct] = __builtin_amdgcn_mfma_f32_16x16x32_bf16(Al[rt], Bh, accx[rt][ct], 0, 0, 0);
        accx[rt][ct] = __builtin_amdgcn_mfma_f32_16x16x32_bf16(Ah[rt], Bl, accx[rt][ct], 0, 0, 0);
      }
    }
    __syncthreads();                 // Win[j] consumed
#pragma unroll
    for (int i = 0; i < 4; ++i) *(u16x8*)(pW + wdoff[i]) = wreg[i];  // Wa[j]
    if (j < 3) {
#pragma unroll
      for (int i = 0; i < 4; ++i)
        wreg[i] = *(const u16x8*)(wt + wsoff[i] + kt + 32);          // Win[j+1]
    }
    __syncthreads();                 // pW = Wa[j]
#pragma unroll
    for (int ct = 0; ct < 4; ++ct) {
      const int cb = (wc * 64 + ct * 16 + ln) * 128;
      const bf16x8 Bh = *(const bf16x8*)(pW + cb + ((gk) ^ csw));
      const bf16x8 Bl = *(const bf16x8*)(pW + cb + ((64 + gk) ^ csw));
#pragma unroll
      for (int rt = 0; rt < 2; ++rt) {
        acca[rt][ct] = __builtin_amdgcn_mfma_f32_16x16x32_bf16(Ah[rt], Bh, acca[rt][ct], 0, 0, 0);
        acca[rt][ct] = __builtin_amdgcn_mfma_f32_16x16x32_bf16(Al[rt], Bh, acca[rt][ct], 0, 0, 0);
        acca[rt][ct] = __builtin_amdgcn_mfma_f32_16x16x32_bf16(Ah[rt], Bl, acca[rt][ct], 0, 0, 0);
      }
    }
    __syncthreads();                 // Wa[j] consumed
    if (j < 3) {
#pragma unroll
      for (int i = 0; i < 4; ++i) *(u16x8*)(pW + wdoff[i]) = wreg[i];  // Win[j+1]
#pragma unroll
      for (int i = 0; i < 4; ++i)
        wreg[i] = *(const u16x8*)(wt + wsoff[i] + 262144 + kt + 32);   // Wa[j+1]
    }
  }
  // after last consumed-barrier: pW region free for pSeg.

  // ---- gates into registers (arithmetic identical to R6) ----
  float av_sav[2][4][4], xn_sav[2][4][4];
#pragma unroll
  for (int ct = 0; ct < 4; ++ct) {
    const int col = wc * 64 + ct * 16 + ln;
    const float bi  = b_in[h * BWID + col];
    const float ba  = b_a[h * BWID + col];
    const float spv = sp[h * BWID + col];
#pragma unroll
    for (int rt = 0; rt < 2; ++rt) {
#pragma unroll
      for (int r = 0; r < 4; ++r) {
        const int row = wr * 32 + rt * 16 + g * 4 + r;  // C/D layout (m89)
        const float zx = accx[rt][ct][r] + bi;
        const float za = acca[rt][ct][r] + ba;
        const int xoff = row * 256 + ((col * 2) ^ ((row & 15) << 4));
        const float xv = bf_f(*(const unsigned short*)(pXh + xoff)) +
                         bf_f(*(const unsigned short*)(pXl + xoff));
        const float gx = __builtin_amdgcn_rcpf(1.f + __expf(-zx));
        const float ga = __builtin_amdgcn_rcpf(1.f + __expf(-za));
        const float la = -POWERF * ga * spv;
        const float av = __expf(la);
        const float asq = __expf(2.f * la);
        av_sav[rt][ct][r] = av;
        xn_sav[rt][ct][r] = xv * gx * sqrtf(fmaxf(1.f - asq, 0.f));
      }
    }
  }

  // ---- segment partials (4 consecutive timesteps each) -> pSeg ----
#pragma unroll
  for (int ct = 0; ct < 4; ++ct) {
    const int col = wc * 64 + ct * 16 + ln;
#pragma unroll
    for (int rt = 0; rt < 2; ++rt) {
      float A4 = 1.f, h4 = 0.f;
#pragma unroll
      for (int r = 0; r < 4; ++r) {
        h4 = fmaf(av_sav[rt][ct][r], h4, xn_sav[rt][ct][r]);
        A4 *= av_sav[rt][ct][r];
      }
      const int s = wr * 8 + rt * 4 + g;   // time-ordered segment index
      *(float2*)(pSeg + col * 128 + ((s * 8) ^ ((col & 15) << 3))) =
          make_float2(A4, h4);
    }
  }
  __syncthreads();

  // ---- scan threads: compose segments, carry wait/publish, prefix-h ----
  if (tid < 128) {
    const int w = tid;
    float As[16], hs[16];
#pragma unroll
    for (int s = 0; s < 16; ++s) {
      const float2 v =
          *(const float2*)(pSeg + w * 128 + ((s * 8) ^ ((w & 15) << 3)));
      As[s] = v.x;
      hs[s] = v.y;
    }
    float hprev = 0.f;
    if (rc > 0) {
      const unsigned long long* srcw =
          hcarry + (size_t)(vbid - NCHAIN) * 128 + w;
      unsigned long long wv = __hip_atomic_load(srcw, __ATOMIC_RELAXED,
                                                __HIP_MEMORY_SCOPE_AGENT);
      int spins = 0;
      while ((wv >> 32) == 0ull) {
        __builtin_amdgcn_s_sleep(1);
        if (++spins > (1 << 18)) break;   // poison-on-timeout, never hang
        wv = __hip_atomic_load(srcw, __ATOMIC_RELAXED,
                               __HIP_MEMORY_SCOPE_AGENT);
      }
      hprev = __uint_as_float((unsigned)(wv & 0xffffffffull));
    }
    float p = hprev;                      // exclusive prefix per segment
#pragma unroll
    for (int s = 0; s < 16; ++s) {
      *(float*)(pSeg + w * 128 + ((s * 8) ^ ((w & 15) << 3))) = p;
      p = fmaf(As[s], p, hs[s]);          // affine compose (== scan_carry op)
    }
    __hip_atomic_store(hcarry + (size_t)vbid * 128 + w,
                       (1ull << 32) | (unsigned long long)__float_as_uint(p),
                       __ATOMIC_RELAXED, __HIP_MEMORY_SCOPE_AGENT);
  }
  __syncthreads();

  // ---- owners: rescan 4 rows from prefix, store out from regs ----
#pragma unroll
  for (int ct = 0; ct < 4; ++ct) {
    const int col = wc * 64 + ct * 16 + ln;
#pragma unroll
    for (int rt = 0; rt < 2; ++rt) {
      const int s = wr * 8 + rt * 4 + g;
      float hh =
          *(const float*)(pSeg + col * 128 + ((s * 8) ^ ((col & 15) << 3)));
#pragma unroll
      for (int r = 0; r < 4; ++r) {
        hh = fmaf(av_sav[rt][ct][r], hh, xn_sav[rt][ct][r]);
        out[xbase + (size_t)(wr * 32 + rt * 16 + g * 4 + r) * NW + col] = hh;
      }
    }
  }
}

extern "C" void kernel_launch(void* const* d_in, const int* in_sizes, int n_in,
                              void* d_out, int out_size, void* d_ws, size_t ws_size,
                              hipStream_t stream) {
  const float* x       = (const float*)d_in[0];
  const float* a_param = (const float*)d_in[1];
  const float* w_in    = (const float*)d_in[2];
  const float* b_in    = (const float*)d_in[3];
  const float* w_a     = (const float*)d_in[4];
  const float* b_a     = (const float*)d_in[5];
  float* out = (float*)d_out;

  // Workspace (~5.3 MB): hcarry[4096*128] u64 @0 (4 MB), ticket, wt (1 MB),
  // sp (4 KB). prep re-zeroes hcarry/ticket each launch (graph-replay safe).
  char* ws = (char*)d_ws;
  unsigned long long* hcarry = (unsigned long long*)ws;        // 4 MB
  int* ticket = (int*)(ws + (4 << 20));
  unsigned short* wt = (unsigned short*)(ws + (4 << 20) + 1024);  // 1 MB
  float* sp = (float*)(ws + (4 << 20) + 1024 + (1 << 20));

  prep_kernel<<<1024, 256, 0, stream>>>(w_in, w_a, a_param, wt, sp,
                                        hcarry, ticket);
  fused_kernel<<<NBLK, 256, 0, stream>>>(x, wt, sp, b_in, b_a, out,
                                         ticket, hcarry);
}

// Round 8
// 298.990 us; speedup vs baseline: 10.8198x; 1.0648x over previous
//
#include <hip/hip_runtime.h>
#include <math.h>

// RG-LRU single-pass: B=4, L=8192, W=1024, H=8, bw=128.
#define NB 4
#define NL 8192
#define NW 1024
#define NH 8
#define BWID 128
#define POWERF 8.0f

#define TM 64                 // timesteps per block == scan chunk
#define NRC (NL / TM)         // 128 chunks per sequence
#define NCHAIN (NB * NH)      // 32 independent scan chains
#define NBLK (NRC * NCHAIN)   // 4096 blocks

typedef __attribute__((ext_vector_type(8))) short bf16x8;          // MFMA A/B frag
typedef __attribute__((ext_vector_type(8))) unsigned short u16x8;  // raw 16B move
typedef __attribute__((ext_vector_type(4))) float f32x4;           // MFMA C/D frag

__device__ __forceinline__ unsigned short bf_hi(float f) {
  return (unsigned short)(__float_as_uint(f) >> 16);  // truncate to bf16
}
__device__ __forceinline__ float bf_f(unsigned short h) {
  return __uint_as_float(((unsigned)h) << 16);
}

// ---------------- prep: W^T bf16 hi/lo, softplus(a_param), zero sync state --
// wt layout: [mat(2)][split(2)][h(8)][col(128)][k(128)] ushort (1 MB total).
// carry layout: [vbid(4096)][chan(128)][2] u64 — word0 = inclusive
// (tag = hi-word nonzero, lo = H bits), word1 = local (tag = sign bit of
// hi-word A field — A >= +0 always so sign is free; lo = h bits). 8 MB.
__global__ void prep_kernel(const float* __restrict__ w_in,
                            const float* __restrict__ w_a,
                            const float* __restrict__ a_param,
                            unsigned short* __restrict__ wt,
                            float* __restrict__ sp,
                            unsigned long long* __restrict__ carry,
                            int* __restrict__ ticket) {
  const int gtid = blockIdx.x * 256 + threadIdx.x;  // 0..262143
  const int k   = gtid & 127;
  const int col = (gtid >> 7) & 127;
  const int hh  = (gtid >> 14) & 7;
  const int mat = gtid >> 17;
  const float* src = mat ? w_a : w_in;
  const float v = src[((size_t)hh * 128 + k) * 128 + col];  // W[h][k][col]
  const unsigned short hi = bf_hi(v);
  const unsigned short lo = bf_hi(v - bf_f(hi));
  wt[(((size_t)(mat * 2 + 0) * 8 + hh) * 128 + col) * 128 + k] = hi;
  wt[(((size_t)(mat * 2 + 1) * 8 + hh) * 128 + col) * 128 + k] = lo;
  if (gtid < NW) sp[gtid] = log1pf(expf(a_param[gtid]));
  const size_t ci = (size_t)gtid * 4;   // zero NBLK*128*2 words (8 MB)
  carry[ci] = 0ull;
  carry[ci + 1] = 0ull;
  carry[ci + 2] = 0ull;
  carry[ci + 3] = 0ull;
  if (gtid == 0) *ticket = 0;
}

// ---------------- fused: MFMA gates + segmented scan + lookback carry -------
// GEMM/gates/segments identical to R7 (48 KB LDS, 3 blocks/CU).
// Carry: decoupled lookback. Every block publishes its LOCAL (A,h) in one
// tagged u64 unconditionally after the local scan (no wait). hprev is found
// by walking predecessors: inclusive if ready (fast path == R7 math), else
// consume their local and step back (one 16B line per step). Inclusive is
// published ONE fma after hprev. The 128-hop serial chain (R6/R7's ~1.3us
// per hop critical path) is replaced by parallel local publication + a
// typically 1-2 deep walk.
__global__ __launch_bounds__(256, 3)
void fused_kernel(const float* __restrict__ x,
                  const unsigned short* __restrict__ wt,
                  const float* __restrict__ sp,
                  const float* __restrict__ b_in,
                  const float* __restrict__ b_a,
                  float* __restrict__ out,
                  int* __restrict__ ticket,
                  unsigned long long* __restrict__ carry) {
  __shared__ char smem[49152];
  char* const pXh = smem;            // 16 KB u16 [64][128] swz ((row&15)<<4)
  char* const pXl = smem + 16384;    // 16 KB
  char* const pW  = smem + 32768;    // 16 KB u16 [col(128)][split(2)][kk(32)] swz
  char* const pSeg = smem + 32768;   // 16 KB f32x2 [col(128)][seg(16)] (over pW)

  const int tid  = threadIdx.x;
  // ---- ticket: decouples work-id from dispatch order ----
  if (tid == 0) *(int*)smem = atomicAdd(ticket, 1);
  __syncthreads();
  const int vbid = *(const int*)smem;
  __syncthreads();                   // vbid read by all before smem reuse
  const int rc = vbid >> 5;          // chunk index (layer-major)
  const int bh = vbid & 31;
  const int b  = bh >> 3;
  const int h  = bh & 7;

  const int lane = tid & 63;
  const int wid  = tid >> 6;
  const int g  = lane >> 4;   // k-group 0..3
  const int ln = lane & 15;
  const int wr = wid >> 1;    // row half (32 rows)
  const int wc = wid & 1;     // col half (64 cols)

  const size_t xbase = ((size_t)b * NL + (size_t)rc * TM) * NW + h * BWID;

  // ---- W stage addressing: 1024 16B chunks/phase = 4/thread ----
  int wsoff[4], wdoff[4];
#pragma unroll
  for (int i = 0; i < 4; ++i) {
    const int chunk = tid + 256 * i;   // 0..1023
    const int split = chunk >> 9;      // 0:hi 1:lo
    const int rem = chunk & 511;
    const int col = rem >> 2;
    const int kk8 = (rem & 3) * 8;
    wsoff[i] = split * 131072 + h * 16384 + col * 128 + kk8;  // +mat*262144+kt
    wdoff[i] = col * 128 + ((split * 64 + kk8 * 2) ^ ((col & 7) << 4));
  }
  u16x8 wreg[4];
#pragma unroll
  for (int i = 0; i < 4; ++i) wreg[i] = *(const u16x8*)(wt + wsoff[i]);  // Win[0]

  // ---- stage X as bf16 hi/lo (overlaps W loads) ----
#pragma unroll
  for (int i = 0; i < 4; ++i) {
    const int chunk = tid + 256 * i;      // 0..1023
    const int row = chunk >> 4;
    const int k8  = (chunk & 15) * 8;
    const float4 v0 = *(const float4*)(x + xbase + (size_t)row * NW + k8);
    const float4 v1 = *(const float4*)(x + xbase + (size_t)row * NW + k8 + 4);
    const float f[8] = {v0.x, v0.y, v0.z, v0.w, v1.x, v1.y, v1.z, v1.w};
    u16x8 vh, vl;
#pragma unroll
    for (int j = 0; j < 8; ++j) {
      const unsigned short hi = bf_hi(f[j]);
      vh[j] = hi;
      vl[j] = bf_hi(f[j] - bf_f(hi));
    }
    const int off = row * 256 + ((k8 * 2) ^ ((row & 15) << 4));
    *(u16x8*)(pXh + off) = vh;
    *(u16x8*)(pXl + off) = vl;
  }
  __syncthreads();                 // X staged; pW untouched
#pragma unroll
  for (int i = 0; i < 4; ++i) *(u16x8*)(pW + wdoff[i]) = wreg[i];  // Win[0]
#pragma unroll
  for (int i = 0; i < 4; ++i)
    wreg[i] = *(const u16x8*)(wt + wsoff[i] + 262144);             // Wa[0]

  f32x4 accx[2][4], acca[2][4];
#pragma unroll
  for (int rt = 0; rt < 2; ++rt)
#pragma unroll
    for (int ct = 0; ct < 4; ++ct) {
      accx[rt][ct] = (f32x4){0.f, 0.f, 0.f, 0.f};
      acca[rt][ct] = (f32x4){0.f, 0.f, 0.f, 0.f};
    }

  const int csw = (ln & 7) << 4;     // B-frag swizzle (col&7 == ln&7)
  const int gk  = g * 16;

#pragma unroll 1
  for (int j = 0; j < 4; ++j) {
    const int kt = j * 32;
    __syncthreads();                 // pW = Win[j]
    bf16x8 Ah[2], Al[2];
#pragma unroll
    for (int rt = 0; rt < 2; ++rt) {
      const int arow = wr * 32 + rt * 16 + ln;
      const int abyte = arow * 256 + (((kt + g * 8) * 2) ^ ((arow & 15) << 4));
      Ah[rt] = *(const bf16x8*)(pXh + abyte);
      Al[rt] = *(const bf16x8*)(pXl + abyte);
    }
#pragma unroll
    for (int ct = 0; ct < 4; ++ct) {
      const int cb = (wc * 64 + ct * 16 + ln) * 128;
      const bf16x8 Bh = *(const bf16x8*)(pW + cb + ((gk) ^ csw));
      const bf16x8 Bl = *(const bf16x8*)(pW + cb + ((64 + gk) ^ csw));
#pragma unroll
      for (int rt = 0; rt < 2; ++rt) {
        accx[rt][ct] = __builtin_amdgcn_mfma_f32_16x16x32_bf16(Ah[rt], Bh, accx[rt][ct], 0, 0, 0);
        accx[rt][ct] = __builtin_amdgcn_mfma_f32_16x16x32_bf16(Al[rt], Bh, accx[rt][ct], 0, 0, 0);
        accx[rt][ct] = __builtin_amdgcn_mfma_f32_16x16x32_bf16(Ah[rt], Bl, accx[rt][ct], 0, 0, 0);
      }
    }
    __syncthreads();                 // Win[j] consumed
#pragma unroll
    for (int i = 0; i < 4; ++i) *(u16x8*)(pW + wdoff[i]) = wreg[i];  // Wa[j]
    if (j < 3) {
#pragma unroll
      for (int i = 0; i < 4; ++i)
        wreg[i] = *(const u16x8*)(wt + wsoff[i] + kt + 32);          // Win[j+1]
    }
    __syncthreads();                 // pW = Wa[j]
#pragma unroll
    for (int ct = 0; ct < 4; ++ct) {
      const int cb = (wc * 64 + ct * 16 + ln) * 128;
      const bf16x8 Bh = *(const bf16x8*)(pW + cb + ((gk) ^ csw));
      const bf16x8 Bl = *(const bf16x8*)(pW + cb + ((64 + gk) ^ csw));
#pragma unroll
      for (int rt = 0; rt < 2; ++rt) {
        acca[rt][ct] = __builtin_amdgcn_mfma_f32_16x16x32_bf16(Ah[rt], Bh, acca[rt][ct], 0, 0, 0);
        acca[rt][ct] = __builtin_amdgcn_mfma_f32_16x16x32_bf16(Al[rt], Bh, acca[rt][ct], 0, 0, 0);
        acca[rt][ct] = __builtin_amdgcn_mfma_f32_16x16x32_bf16(Ah[rt], Bl, acca[rt][ct], 0, 0, 0);
      }
    }
    __syncthreads();                 // Wa[j] consumed
    if (j < 3) {
#pragma unroll
      for (int i = 0; i < 4; ++i) *(u16x8*)(pW + wdoff[i]) = wreg[i];  // Win[j+1]
#pragma unroll
      for (int i = 0; i < 4; ++i)
        wreg[i] = *(const u16x8*)(wt + wsoff[i] + 262144 + kt + 32);   // Wa[j+1]
    }
  }
  // after last consumed-barrier: pW region free for pSeg.

  // ---- gates into registers (arithmetic identical to R7) ----
  float av_sav[2][4][4], xn_sav[2][4][4];
#pragma unroll
  for (int ct = 0; ct < 4; ++ct) {
    const int col = wc * 64 + ct * 16 + ln;
    const float bi  = b_in[h * BWID + col];
    const float ba  = b_a[h * BWID + col];
    const float spv = sp[h * BWID + col];
#pragma unroll
    for (int rt = 0; rt < 2; ++rt) {
#pragma unroll
      for (int r = 0; r < 4; ++r) {
        const int row = wr * 32 + rt * 16 + g * 4 + r;  // C/D layout (m89)
        const float zx = accx[rt][ct][r] + bi;
        const float za = acca[rt][ct][r] + ba;
        const int xoff = row * 256 + ((col * 2) ^ ((row & 15) << 4));
        const float xv = bf_f(*(const unsigned short*)(pXh + xoff)) +
                         bf_f(*(const unsigned short*)(pXl + xoff));
        const float gx = __builtin_amdgcn_rcpf(1.f + __expf(-zx));
        const float ga = __builtin_amdgcn_rcpf(1.f + __expf(-za));
        const float la = -POWERF * ga * spv;
        const float av = __expf(la);
        const float asq = __expf(2.f * la);
        av_sav[rt][ct][r] = av;
        xn_sav[rt][ct][r] = xv * gx * sqrtf(fmaxf(1.f - asq, 0.f));
      }
    }
  }

  // ---- segment partials (4 consecutive timesteps each) -> pSeg ----
#pragma unroll
  for (int ct = 0; ct < 4; ++ct) {
    const int col = wc * 64 + ct * 16 + ln;
#pragma unroll
    for (int rt = 0; rt < 2; ++rt) {
      float A4 = 1.f, h4 = 0.f;
#pragma unroll
      for (int r = 0; r < 4; ++r) {
        h4 = fmaf(av_sav[rt][ct][r], h4, xn_sav[rt][ct][r]);
        A4 *= av_sav[rt][ct][r];
      }
      const int s = wr * 8 + rt * 4 + g;   // time-ordered segment index
      *(float2*)(pSeg + col * 128 + ((s * 8) ^ ((col & 15) << 3))) =
          make_float2(A4, h4);
    }
  }
  __syncthreads();

  // ---- scan threads: local compose, publish local, lookback, publish incl --
  if (tid < 128) {
    const int w = tid;
    float As[16], hs[16];
#pragma unroll
    for (int s = 0; s < 16; ++s) {
      const float2 v =
          *(const float2*)(pSeg + w * 128 + ((s * 8) ^ ((w & 15) << 3)));
      As[s] = v.x;
      hs[s] = v.y;
    }
    // local inclusive over this chunk (hprev = 0)
    float Atot = 1.f, hloc = 0.f;
#pragma unroll
    for (int s = 0; s < 16; ++s) {
      hloc = fmaf(As[s], hloc, hs[s]);
      Atot *= As[s];
    }
    // publish LOCAL unconditionally: hi = A with sign flipped (tag), lo = h
    const size_t cbase = ((size_t)vbid * 128 + w) * 2;
    __hip_atomic_store(carry + cbase + 1,
                       ((unsigned long long)__float_as_uint(-Atot) << 32) |
                           (unsigned long long)__float_as_uint(hloc),
                       __ATOMIC_RELAXED, __HIP_MEMORY_SCOPE_AGENT);

    // lookback: inclusive fast path, else consume locals walking down
    float hprev = 0.f;
    if (rc > 0) {
      float P = 1.f, q = 0.f;
      int j = vbid - NCHAIN;
      int spins = 0;
      while (true) {
        const size_t jb = ((size_t)j * 128 + w) * 2;
        const unsigned long long wi = __hip_atomic_load(
            carry + jb, __ATOMIC_RELAXED, __HIP_MEMORY_SCOPE_AGENT);
        if (wi >> 32) {               // inclusive ready
          hprev = fmaf(P, __uint_as_float((unsigned)wi), q);
          break;
        }
        const unsigned long long wl = __hip_atomic_load(
            carry + jb + 1, __ATOMIC_RELAXED, __HIP_MEMORY_SCOPE_AGENT);
        if (wl >> 63) {               // local ready: compose, step back
          const float Aj = -__uint_as_float((unsigned)(wl >> 32));
          const float hj = __uint_as_float((unsigned)wl);
          q = fmaf(P, hj, q);
          P *= Aj;
          if (j < NCHAIN) { hprev = q; break; }   // hit layer 0
          j -= NCHAIN;
          continue;
        }
        __builtin_amdgcn_s_sleep(1);
        if (++spins > (1 << 18)) { hprev = q; break; }  // poison, never hang
      }
    }
    // publish INCLUSIVE one fma after hprev (minimizes residual hop)
    const float Hm = fmaf(Atot, hprev, hloc);
    __hip_atomic_store(carry + cbase,
                       (1ull << 32) | (unsigned long long)__float_as_uint(Hm),
                       __ATOMIC_RELAXED, __HIP_MEMORY_SCOPE_AGENT);

    // exclusive prefix per segment for the owner threads
    float p = hprev;
#pragma unroll
    for (int s = 0; s < 16; ++s) {
      *(float*)(pSeg + w * 128 + ((s * 8) ^ ((w & 15) << 3))) = p;
      p = fmaf(As[s], p, hs[s]);
    }
  }
  __syncthreads();

  // ---- owners: rescan 4 rows from prefix, store out from regs ----
#pragma unroll
  for (int ct = 0; ct < 4; ++ct) {
    const int col = wc * 64 + ct * 16 + ln;
#pragma unroll
    for (int rt = 0; rt < 2; ++rt) {
      const int s = wr * 8 + rt * 4 + g;
      float hh =
          *(const float*)(pSeg + col * 128 + ((s * 8) ^ ((col & 15) << 3)));
#pragma unroll
      for (int r = 0; r < 4; ++r) {
        hh = fmaf(av_sav[rt][ct][r], hh, xn_sav[rt][ct][r]);
        out[xbase + (size_t)(wr * 32 + rt * 16 + g * 4 + r) * NW + col] = hh;
      }
    }
  }
}

extern "C" void kernel_launch(void* const* d_in, const int* in_sizes, int n_in,
                              void* d_out, int out_size, void* d_ws, size_t ws_size,
                              hipStream_t stream) {
  const float* x       = (const float*)d_in[0];
  const float* a_param = (const float*)d_in[1];
  const float* w_in    = (const float*)d_in[2];
  const float* b_in    = (const float*)d_in[3];
  const float* w_a     = (const float*)d_in[4];
  const float* b_a     = (const float*)d_in[5];
  float* out = (float*)d_out;

  // Workspace (~9.3 MB): carry[4096][128][2] u64 @0 (8 MB), ticket, wt (1 MB),
  // sp (4 KB). prep re-zeroes carry/ticket each launch (graph-replay safe).
  char* ws = (char*)d_ws;
  unsigned long long* carry = (unsigned long long*)ws;         // 8 MB
  int* ticket = (int*)(ws + (8 << 20));
  unsigned short* wt = (unsigned short*)(ws + (8 << 20) + 1024);  // 1 MB
  float* sp = (float*)(ws + (8 << 20) + 1024 + (1 << 20));

  prep_kernel<<<1024, 256, 0, stream>>>(w_in, w_a, a_param, wt, sp,
                                        carry, ticket);
  fused_kernel<<<NBLK, 256, 0, stream>>>(x, wt, sp, b_in, b_a, out,
                                         ticket, carry);
}